// Round 1
// baseline (280.160 us; speedup 1.0000x reference)
//
#include <hip/hip_runtime.h>
#include <math.h>

// HardTripletLoss: B=4096, D=512, labels in [0,64), margin 0.5, scalar fp32 out.
// ws layout (floats): [0,4096)=hp, [4096,8192)=hn, [8192,12288)=norms, [12288,+64 ints)=cnt

#define NB 4096
#define ND 512
#define NLAB 64

__global__ __launch_bounds__(256) void k_init(float* __restrict__ hp, float* __restrict__ hn) {
    int i = blockIdx.x * 256 + threadIdx.x;
    if (i < NB) {
        hp[i] = 0.0f;                        // max identity (all dists >= 0)
        hn[i] = __int_as_float(0x7F800000);  // +inf
    }
}

__global__ __launch_bounds__(1024) void k_hist(const int* __restrict__ labels, int* __restrict__ cnt) {
    __shared__ int h[NLAB];
    if (threadIdx.x < NLAB) h[threadIdx.x] = 0;
    __syncthreads();
    for (int i = threadIdx.x; i < NB; i += 1024) atomicAdd(&h[labels[i]], 1);
    __syncthreads();
    if (threadIdx.x < NLAB) cnt[threadIdx.x] = h[threadIdx.x];
}

// One wave (64 lanes) per row: 512 floats = 2 x float4 per lane, shuffle reduce.
__global__ __launch_bounds__(256) void k_norms(const float* __restrict__ x, float* __restrict__ norms) {
    int wave = threadIdx.x >> 6;
    int lane = threadIdx.x & 63;
    int row  = blockIdx.x * 4 + wave;
    const float* p = x + (size_t)row * ND;
    float4 v0 = *(const float4*)(p + lane * 4);
    float4 v1 = *(const float4*)(p + 256 + lane * 4);
    float s = v0.x*v0.x + v0.y*v0.y + v0.z*v0.z + v0.w*v0.w
            + v1.x*v1.x + v1.y*v1.y + v1.z*v1.z + v1.w*v1.w;
    #pragma unroll
    for (int m = 1; m < 64; m <<= 1) s += __shfl_xor(s, m);
    if (lane == 0) norms[row] = s;
}

// 128x128 tile per block, 256 threads (16x16), 8x8 micro-tile per thread, BK=16.
__global__ __launch_bounds__(256) void k_dist_reduce(
    const float* __restrict__ x, const int* __restrict__ labels,
    const float* __restrict__ norms, float* __restrict__ hp, float* __restrict__ hn)
{
    __shared__ float As[16][132];  // k-major, +4 pad (keeps b128 16B-aligned, breaks conflicts)
    __shared__ float Bs[16][132];

    const int tid = threadIdx.x;
    const int tx = tid & 15;       // column group
    const int ty = tid >> 4;       // row group
    const int rb = blockIdx.y * 128;
    const int cb = blockIdx.x * 128;

    float acc[8][8];
    #pragma unroll
    for (int i = 0; i < 8; ++i)
        #pragma unroll
        for (int j = 0; j < 8; ++j) acc[i][j] = 0.0f;

    for (int kb = 0; kb < ND; kb += 16) {
        // Stage A and B tiles (rows of x, transposed into k-major LDS).
        #pragma unroll
        for (int l = 0; l < 2; ++l) {
            int f   = tid + l * 256;       // 0..511 float4 slots
            int row = f >> 2;              // 0..127
            int c4  = (f & 3) * 4;         // 0,4,8,12
            float4 av = *(const float4*)(x + (size_t)(rb + row) * ND + kb + c4);
            As[c4 + 0][row] = av.x; As[c4 + 1][row] = av.y;
            As[c4 + 2][row] = av.z; As[c4 + 3][row] = av.w;
            float4 bv = *(const float4*)(x + (size_t)(cb + row) * ND + kb + c4);
            Bs[c4 + 0][row] = bv.x; Bs[c4 + 1][row] = bv.y;
            Bs[c4 + 2][row] = bv.z; Bs[c4 + 3][row] = bv.w;
        }
        __syncthreads();

        #pragma unroll
        for (int kk = 0; kk < 16; ++kk) {
            float a[8], b[8];
            *(float4*)&a[0] = *(const float4*)&As[kk][ty * 8];
            *(float4*)&a[4] = *(const float4*)&As[kk][ty * 8 + 4];
            *(float4*)&b[0] = *(const float4*)&Bs[kk][tx * 8];
            *(float4*)&b[4] = *(const float4*)&Bs[kk][tx * 8 + 4];
            #pragma unroll
            for (int i = 0; i < 8; ++i)
                #pragma unroll
                for (int j = 0; j < 8; ++j)
                    acc[i][j] = fmaf(a[i], b[j], acc[i][j]);
        }
        __syncthreads();
    }

    // Epilogue: dot -> dist, masks, per-row tile reduction, one atomic per row.
    int rows[8], cols[8], lr[8], lc[8];
    float nr[8], nc[8];
    #pragma unroll
    for (int i = 0; i < 8; ++i) {
        rows[i] = rb + ty * 8 + i;
        nr[i] = norms[rows[i]];
        lr[i] = labels[rows[i]];
    }
    #pragma unroll
    for (int j = 0; j < 8; ++j) {
        cols[j] = cb + tx * 8 + j;
        nc[j] = norms[cols[j]];
        lc[j] = labels[cols[j]];
    }

    float pmax[8], nmin[8];
    #pragma unroll
    for (int i = 0; i < 8; ++i) {
        pmax[i] = 0.0f;                        // neutral for max over nonneg dists
        nmin[i] = __int_as_float(0x7F800000);  // +inf
        #pragma unroll
        for (int j = 0; j < 8; ++j) {
            float sq = nr[i] + nc[j] - 2.0f * acc[i][j];
            sq = fmaxf(sq, 0.0f);
            float d = sqrtf(sq);
            if (lr[i] == lc[j]) {
                if (rows[i] != cols[j]) pmax[i] = fmaxf(pmax[i], d);
            } else {
                nmin[i] = fminf(nmin[i], d);
            }
        }
    }

    // Reduce across the 16 tx-threads (lane bits 0..3 within the wave).
    #pragma unroll
    for (int m = 1; m <= 8; m <<= 1) {
        #pragma unroll
        for (int i = 0; i < 8; ++i) {
            pmax[i] = fmaxf(pmax[i], __shfl_xor(pmax[i], m));
            nmin[i] = fminf(nmin[i], __shfl_xor(nmin[i], m));
        }
    }
    if (tx == 0) {
        #pragma unroll
        for (int i = 0; i < 8; ++i) {
            // Nonneg floats: int compare == float compare. hp init 0, hn init +inf.
            atomicMax((int*)&hp[rows[i]], __float_as_int(pmax[i]));
            atomicMin((int*)&hn[rows[i]], __float_as_int(nmin[i]));
        }
    }
}

__global__ __launch_bounds__(256) void k_finalize(
    const int* __restrict__ labels, const float* __restrict__ hp,
    const float* __restrict__ hn, const int* __restrict__ cnt, float* __restrict__ out)
{
    int tid = threadIdx.x;
    float s = 0.0f;
    int c = 0;
    for (int i = tid; i < NB; i += 256) {
        int k = cnt[labels[i]];
        bool valid = (k >= 2) && (k < NB);
        if (valid) {
            float per = fmaxf(hp[i] - hn[i] + 0.5f, 0.0f);
            s += per;
            c += 1;
        }
    }
    #pragma unroll
    for (int m = 1; m < 64; m <<= 1) {
        s += __shfl_xor(s, m);
        c += __shfl_xor(c, m);
    }
    __shared__ float sw[4];
    __shared__ int   cw[4];
    int wave = tid >> 6, lane = tid & 63;
    if (lane == 0) { sw[wave] = s; cw[wave] = c; }
    __syncthreads();
    if (tid == 0) {
        float S = sw[0] + sw[1] + sw[2] + sw[3];
        int   C = cw[0] + cw[1] + cw[2] + cw[3];
        out[0] = (C > 0) ? (S / (float)C) : 0.0f;
    }
}

extern "C" void kernel_launch(void* const* d_in, const int* in_sizes, int n_in,
                              void* d_out, int out_size, void* d_ws, size_t ws_size,
                              hipStream_t stream) {
    const float* x      = (const float*)d_in[0];
    const int*   labels = (const int*)d_in[1];
    float* ws    = (float*)d_ws;
    float* hp    = ws;
    float* hn    = ws + NB;
    float* norms = ws + 2 * NB;
    int*   cnt   = (int*)(ws + 3 * NB);
    float* out   = (float*)d_out;

    k_init<<<dim3(NB / 256), dim3(256), 0, stream>>>(hp, hn);
    k_hist<<<dim3(1), dim3(1024), 0, stream>>>(labels, cnt);
    k_norms<<<dim3(NB / 4), dim3(256), 0, stream>>>(x, norms);
    k_dist_reduce<<<dim3(NB / 128, NB / 128), dim3(256), 0, stream>>>(x, labels, norms, hp, hn);
    k_finalize<<<dim3(1), dim3(256), 0, stream>>>(labels, hp, hn, cnt, out);
}

// Round 2
// 138.118 us; speedup vs baseline: 2.0284x; 2.0284x over previous
//
#include <hip/hip_runtime.h>
#include <math.h>

// HardTripletLoss: B=4096, D=512, labels in [0,64), margin 0.5, scalar fp32 out.
// Strategy: Gram matrix via bf16 MFMA (inputs truncated to bf16; error ~3e-3 on
// distances of ~32, far under the 0.113 absmax threshold), exact fp32 norms.
//
// ws layout (floats): [0,4096)=hp, [4096,8192)=hn, [8192,12288)=norms,
//                     [12288,+64 ints)=cnt, [16384, +2M ushorts)=xhi (4 MB)

#define NB 4096
#define ND 512
#define NLAB 64
#define LDK 40  // padded LDS row stride in ushorts (80 B): 2-way banks only

typedef __attribute__((ext_vector_type(8))) short short8;
typedef __attribute__((ext_vector_type(4))) float f32x4;

__global__ __launch_bounds__(256) void k_init(float* __restrict__ hp, float* __restrict__ hn) {
    int i = blockIdx.x * 256 + threadIdx.x;
    if (i < NB) {
        hp[i] = 0.0f;                        // max identity (dists >= 0)
        hn[i] = __int_as_float(0x7F800000);  // +inf
    }
}

__global__ __launch_bounds__(1024) void k_hist(const int* __restrict__ labels, int* __restrict__ cnt) {
    __shared__ int h[NLAB];
    if (threadIdx.x < NLAB) h[threadIdx.x] = 0;
    __syncthreads();
    for (int i = threadIdx.x; i < NB; i += 1024) atomicAdd(&h[labels[i]], 1);
    __syncthreads();
    if (threadIdx.x < NLAB) cnt[threadIdx.x] = h[threadIdx.x];
}

__device__ __forceinline__ ushort bf16rn(float f) {
    unsigned u = __float_as_uint(f);
    u += 0x7FFF + ((u >> 16) & 1);  // round-to-nearest-even
    return (ushort)(u >> 16);
}

// fp32 -> bf16, 4 elems/thread. 4096*512/4 = 512K float4 -> 2048 blocks x 256.
__global__ __launch_bounds__(256) void k_convert(const float* __restrict__ x, ushort* __restrict__ xhi) {
    int i = blockIdx.x * 256 + threadIdx.x;
    float4 v = ((const float4*)x)[i];
    ushort4 h;
    h.x = bf16rn(v.x); h.y = bf16rn(v.y); h.z = bf16rn(v.z); h.w = bf16rn(v.w);
    ((ushort4*)xhi)[i] = h;
}

// One wave per row: exact fp32 norms from the original input.
__global__ __launch_bounds__(256) void k_norms(const float* __restrict__ x, float* __restrict__ norms) {
    int wave = threadIdx.x >> 6;
    int lane = threadIdx.x & 63;
    int row  = blockIdx.x * 4 + wave;
    const float* p = x + (size_t)row * ND;
    float4 v0 = *(const float4*)(p + lane * 4);
    float4 v1 = *(const float4*)(p + 256 + lane * 4);
    float s = v0.x*v0.x + v0.y*v0.y + v0.z*v0.z + v0.w*v0.w
            + v1.x*v1.x + v1.y*v1.y + v1.z*v1.z + v1.w*v1.w;
    #pragma unroll
    for (int m = 1; m < 64; m <<= 1) s += __shfl_xor(s, m);
    if (lane == 0) norms[row] = s;
}

// 128x128 tile, 256 threads = 4 waves, each wave a 64x64 quadrant = 4x4 MFMA
// tiles of 16x16x32 bf16. Manual LDS staging with +8-ushort row pad.
__global__ __launch_bounds__(256) void k_dist_mfma(
    const ushort* __restrict__ xhi, const int* __restrict__ labels,
    const float* __restrict__ norms, float* __restrict__ hp, float* __restrict__ hn)
{
    __shared__ ushort As[128 * LDK];
    __shared__ ushort Bs[128 * LDK];

    const int tid  = threadIdx.x;
    const int wave = tid >> 6;
    const int lane = tid & 63;
    const int rb = blockIdx.y * 128;
    const int cb = blockIdx.x * 128;
    const int wr = (wave >> 1) * 64;
    const int wc = (wave & 1) * 64;

    f32x4 acc[4][4];
    #pragma unroll
    for (int mi = 0; mi < 4; ++mi)
        #pragma unroll
        for (int ni = 0; ni < 4; ++ni)
            acc[mi][ni] = (f32x4){0.f, 0.f, 0.f, 0.f};

    // Staging assignment: threads 0..127 stage A rows, 128..255 stage B rows.
    // Each thread: one row's 32-k chunk = 64 B = 4 x uint4.
    const int srow = tid & 127;
    const ushort* gsrc = xhi + (size_t)(((tid < 128) ? rb : cb) + srow) * ND;
    ushort* sdst = ((tid < 128) ? As : Bs) + srow * LDK;

    const int fr = lane & 15;         // fragment row within 16-tile
    const int fo = (lane >> 4) * 8;   // fragment k-offset (ushorts)

    for (int kb = 0; kb < ND; kb += 32) {
        const uint4* g = (const uint4*)(gsrc + kb);
        uint4 v0 = g[0], v1 = g[1], v2 = g[2], v3 = g[3];
        uint4* d = (uint4*)sdst;      // 80 B row stride: 16B-aligned
        d[0] = v0; d[1] = v1; d[2] = v2; d[3] = v3;
        __syncthreads();

        short8 a[4], b[4];
        #pragma unroll
        for (int mi = 0; mi < 4; ++mi)
            a[mi] = *(const short8*)(As + (wr + mi * 16 + fr) * LDK + fo);
        #pragma unroll
        for (int ni = 0; ni < 4; ++ni)
            b[ni] = *(const short8*)(Bs + (wc + ni * 16 + fr) * LDK + fo);

        #pragma unroll
        for (int mi = 0; mi < 4; ++mi)
            #pragma unroll
            for (int ni = 0; ni < 4; ++ni)
                acc[mi][ni] = __builtin_amdgcn_mfma_f32_16x16x32_bf16(
                    a[mi], b[ni], acc[mi][ni], 0, 0, 0);
        __syncthreads();
    }

    // Epilogue: C/D layout col=lane&15, row=(lane>>4)*4+reg (verified m89/m91).
    const int qrow = (lane >> 4) * 4;
    int gcol[4]; float ncol[4]; int lcol[4];
    #pragma unroll
    for (int ni = 0; ni < 4; ++ni) {
        gcol[ni] = cb + wc + ni * 16 + (lane & 15);
        ncol[ni] = norms[gcol[ni]];
        lcol[ni] = labels[gcol[ni]];
    }
    #pragma unroll
    for (int mi = 0; mi < 4; ++mi) {
        #pragma unroll
        for (int reg = 0; reg < 4; ++reg) {
            int grow = rb + wr + mi * 16 + qrow + reg;
            float nr = norms[grow];
            int   lr = labels[grow];
            float pm = 0.0f;
            float nm = __int_as_float(0x7F800000);
            #pragma unroll
            for (int ni = 0; ni < 4; ++ni) {
                float sq = nr + ncol[ni] - 2.0f * acc[mi][ni][reg];
                sq = fmaxf(sq, 0.0f);
                float dd = sqrtf(sq);
                if (lr == lcol[ni]) {
                    if (grow != gcol[ni]) pm = fmaxf(pm, dd);
                } else {
                    nm = fminf(nm, dd);
                }
            }
            #pragma unroll
            for (int m = 1; m <= 8; m <<= 1) {
                pm = fmaxf(pm, __shfl_xor(pm, m));
                nm = fminf(nm, __shfl_xor(nm, m));
            }
            if ((lane & 15) == 0) {
                // Nonneg floats: int compare == float compare.
                atomicMax((int*)&hp[grow], __float_as_int(pm));
                atomicMin((int*)&hn[grow], __float_as_int(nm));
            }
        }
    }
}

__global__ __launch_bounds__(256) void k_finalize(
    const int* __restrict__ labels, const float* __restrict__ hp,
    const float* __restrict__ hn, const int* __restrict__ cnt, float* __restrict__ out)
{
    int tid = threadIdx.x;
    float s = 0.0f;
    int c = 0;
    for (int i = tid; i < NB; i += 256) {
        int k = cnt[labels[i]];
        bool valid = (k >= 2) && (k < NB);
        if (valid) {
            s += fmaxf(hp[i] - hn[i] + 0.5f, 0.0f);
            c += 1;
        }
    }
    #pragma unroll
    for (int m = 1; m < 64; m <<= 1) {
        s += __shfl_xor(s, m);
        c += __shfl_xor(c, m);
    }
    __shared__ float sw[4];
    __shared__ int   cw[4];
    int wave = tid >> 6, lane = tid & 63;
    if (lane == 0) { sw[wave] = s; cw[wave] = c; }
    __syncthreads();
    if (tid == 0) {
        float S = sw[0] + sw[1] + sw[2] + sw[3];
        int   C = cw[0] + cw[1] + cw[2] + cw[3];
        out[0] = (C > 0) ? (S / (float)C) : 0.0f;
    }
}

extern "C" void kernel_launch(void* const* d_in, const int* in_sizes, int n_in,
                              void* d_out, int out_size, void* d_ws, size_t ws_size,
                              hipStream_t stream) {
    const float* x      = (const float*)d_in[0];
    const int*   labels = (const int*)d_in[1];
    float* ws    = (float*)d_ws;
    float* hp    = ws;
    float* hn    = ws + NB;
    float* norms = ws + 2 * NB;
    int*   cnt   = (int*)(ws + 3 * NB);
    ushort* xhi  = (ushort*)(ws + 4 * NB);   // 4096*512 bf16 = 4 MB
    float* out   = (float*)d_out;

    k_convert<<<dim3(NB * ND / 4 / 256), dim3(256), 0, stream>>>(x, xhi);
    k_init<<<dim3(NB / 256), dim3(256), 0, stream>>>(hp, hn);
    k_hist<<<dim3(1), dim3(1024), 0, stream>>>(labels, cnt);
    k_norms<<<dim3(NB / 4), dim3(256), 0, stream>>>(x, norms);
    k_dist_mfma<<<dim3(NB / 128, NB / 128), dim3(256), 0, stream>>>(xhi, labels, norms, hp, hn);
    k_finalize<<<dim3(1), dim3(256), 0, stream>>>(labels, hp, hn, cnt, out);
}

// Round 3
// 108.712 us; speedup vs baseline: 2.5771x; 1.2705x over previous
//
#include <hip/hip_runtime.h>
#include <math.h>

// HardTripletLoss: B=4096, D=512, labels in [0,64), margin 0.5, scalar fp32 out.
// R3: bf16 MFMA Gram, m97-style global_load_lds staging (BK=64) with source-side
// XOR swizzle, upper-triangle blocks only (row+col epilogue, idempotent atomics),
// fused to 3 launches.
//
// ws layout (floats): [0,4096)=hp, [4096,8192)=hn, [8192,12288)=norms,
//                     [12288,16384)=pad, [16384, +2M ushorts)=xhi (4 MB)

#define NB 4096
#define ND 512
#define NLAB 64

typedef __attribute__((ext_vector_type(8))) short short8;
typedef __attribute__((ext_vector_type(4))) float f32x4;

__device__ __forceinline__ ushort bf16rn(float f) {
    unsigned u = __float_as_uint(f);
    u += 0x7FFF + ((u >> 16) & 1);  // round-to-nearest-even
    return (ushort)(u >> 16);
}

__device__ __forceinline__ void gload_lds16(const ushort* g, ushort* l) {
    __builtin_amdgcn_global_load_lds(
        (const __attribute__((address_space(1))) void*)g,
        (__attribute__((address_space(3))) void*)l, 16, 0, 0);
}

// One wave per row: fp32->bf16 convert + exact fp32 norm; init hp/hn.
__global__ __launch_bounds__(256) void k_prep(const float* __restrict__ x,
                                              ushort* __restrict__ xhi,
                                              float* __restrict__ norms,
                                              float* __restrict__ hp,
                                              float* __restrict__ hn) {
    const int wave = threadIdx.x >> 6, lane = threadIdx.x & 63;
    const int row = blockIdx.x * 4 + wave;
    const float* p = x + (size_t)row * ND + lane * 8;
    float4 v0 = *(const float4*)p;
    float4 v1 = *(const float4*)(p + 4);
    ushort h[8];
    h[0] = bf16rn(v0.x); h[1] = bf16rn(v0.y); h[2] = bf16rn(v0.z); h[3] = bf16rn(v0.w);
    h[4] = bf16rn(v1.x); h[5] = bf16rn(v1.y); h[6] = bf16rn(v1.z); h[7] = bf16rn(v1.w);
    *(uint4*)(xhi + (size_t)row * ND + lane * 8) = *(const uint4*)h;
    float s = v0.x*v0.x + v0.y*v0.y + v0.z*v0.z + v0.w*v0.w
            + v1.x*v1.x + v1.y*v1.y + v1.z*v1.z + v1.w*v1.w;
    #pragma unroll
    for (int m = 1; m < 64; m <<= 1) s += __shfl_xor(s, m);
    if (lane == 0) norms[row] = s;
    if (threadIdx.x < 4) {
        hp[blockIdx.x * 4 + threadIdx.x] = 0.0f;
        hn[blockIdx.x * 4 + threadIdx.x] = __int_as_float(0x7F800000);
    }
}

// 128x128 tile, upper-triangle blocks (cb>=rb). 256 threads = 4 waves, each a
// 64x64 quadrant of 4x4 mfma_f32_16x16x32_bf16. BK=64, global_load_lds(16B)
// staging; LDS chunk swizzle phys = logical ^ (row&7) applied at the SOURCE
// address (write side is hw-contiguous), un-applied at fragment reads -> 2-way
// banks (free). Epilogue: row stats (reduce over lane&15) AND col stats
// (reduce over reg + lane>>4) -> symmetric coverage via idempotent atomics.
__global__ __launch_bounds__(256) void k_dist(const ushort* __restrict__ xhi,
                                              const int* __restrict__ labels,
                                              const float* __restrict__ norms,
                                              float* __restrict__ hp,
                                              float* __restrict__ hn) {
    __shared__ ushort As[128 * 64];  // 16 KB, row stride 64 ushorts (128 B)
    __shared__ ushort Bs[128 * 64];

    // Triangular decode: bid -> (r, c) with c >= r, 32x32 block grid, 528 blocks.
    int rem = blockIdx.x, r = 0;
    while (rem >= 32 - r) { rem -= 32 - r; ++r; }
    const int rb = r * 128;
    const int cb = (r + rem) * 128;

    const int tid = threadIdx.x;
    const int w = tid >> 6, lane = tid & 63;
    const int wr = (w >> 1) * 64, wc = (w & 1) * 64;

    f32x4 acc[4][4];
    #pragma unroll
    for (int mi = 0; mi < 4; ++mi)
        #pragma unroll
        for (int ni = 0; ni < 4; ++ni)
            acc[mi][ni] = (f32x4){0.f, 0.f, 0.f, 0.f};

    // Staging: wave w covers rows [w*32, w*32+32) of each tile, 4 instrs each.
    // Lane -> (row = L>>3 within 8-row group, phys chunk = L&7);
    // source logical chunk = (L&7) ^ ((L>>3)&7)  [row&7 == (L>>3)&7].
    const int srow = lane >> 3;
    const int schunk = (lane & 7) ^ (srow & 7);  // logical k-chunk to fetch
    const int q = lane >> 4, fr = lane & 15;

    for (int kb = 0; kb < ND; kb += 64) {
        #pragma unroll
        for (int t = 0; t < 4; ++t) {
            const int rl = w * 32 + t * 8;  // wave-uniform row base
            gload_lds16(xhi + (size_t)(rb + rl + srow) * ND + kb + schunk * 8,
                        As + rl * 64);
            gload_lds16(xhi + (size_t)(cb + rl + srow) * ND + kb + schunk * 8,
                        Bs + rl * 64);
        }
        __syncthreads();  // drains vmcnt -> LDS valid

        #pragma unroll
        for (int kk = 0; kk < 2; ++kk) {
            short8 a[4], b[4];
            #pragma unroll
            for (int mi = 0; mi < 4; ++mi) {
                const int R = wr + mi * 16 + fr;
                const int pc = ((kk << 2) | q) ^ (R & 7);
                a[mi] = *(const short8*)(As + R * 64 + pc * 8);
            }
            #pragma unroll
            for (int ni = 0; ni < 4; ++ni) {
                const int R = wc + ni * 16 + fr;
                const int pc = ((kk << 2) | q) ^ (R & 7);
                b[ni] = *(const short8*)(Bs + R * 64 + pc * 8);
            }
            #pragma unroll
            for (int mi = 0; mi < 4; ++mi)
                #pragma unroll
                for (int ni = 0; ni < 4; ++ni)
                    acc[mi][ni] = __builtin_amdgcn_mfma_f32_16x16x32_bf16(
                        a[mi], b[ni], acc[mi][ni], 0, 0, 0);
        }
        __syncthreads();
    }

    // Epilogue. C/D layout: col = lane&15, row = (lane>>4)*4 + reg.
    int gcol[4]; float ncol[4]; int lcol[4];
    #pragma unroll
    for (int ni = 0; ni < 4; ++ni) {
        gcol[ni] = cb + wc + ni * 16 + fr;
        ncol[ni] = norms[gcol[ni]];
        lcol[ni] = labels[gcol[ni]];
    }
    float pmc[4], nmc[4];  // column-anchored stats (rows of this wave's quadrant)
    #pragma unroll
    for (int ni = 0; ni < 4; ++ni) {
        pmc[ni] = 0.0f;
        nmc[ni] = __int_as_float(0x7F800000);
    }

    #pragma unroll
    for (int mi = 0; mi < 4; ++mi) {
        #pragma unroll
        for (int reg = 0; reg < 4; ++reg) {
            const int grow = rb + wr + mi * 16 + q * 4 + reg;
            const float nr = norms[grow];
            const int lr = labels[grow];
            float pm = 0.0f, nm = __int_as_float(0x7F800000);
            #pragma unroll
            for (int ni = 0; ni < 4; ++ni) {
                float sq = fmaxf(nr + ncol[ni] - 2.0f * acc[mi][ni][reg], 0.0f);
                float dd = sqrtf(sq);
                if (lr == lcol[ni]) {
                    if (grow != gcol[ni]) {
                        pm = fmaxf(pm, dd);
                        pmc[ni] = fmaxf(pmc[ni], dd);
                    }
                } else {
                    nm = fminf(nm, dd);
                    nmc[ni] = fminf(nmc[ni], dd);
                }
            }
            // row stats: reduce over the 16 column-lanes (lane bits 0..3)
            #pragma unroll
            for (int m = 1; m <= 8; m <<= 1) {
                pm = fmaxf(pm, __shfl_xor(pm, m));
                nm = fminf(nm, __shfl_xor(nm, m));
            }
            if (fr == 0) {
                atomicMax((int*)&hp[grow], __float_as_int(pm));
                atomicMin((int*)&hn[grow], __float_as_int(nm));
            }
        }
    }
    // col stats: reduce over the 4 quad-lanes (lane bits 4..5)
    #pragma unroll
    for (int ni = 0; ni < 4; ++ni) {
        #pragma unroll
        for (int m = 16; m <= 32; m <<= 1) {
            pmc[ni] = fmaxf(pmc[ni], __shfl_xor(pmc[ni], m));
            nmc[ni] = fminf(nmc[ni], __shfl_xor(nmc[ni], m));
        }
        if (q == 0) {
            atomicMax((int*)&hp[gcol[ni]], __float_as_int(pmc[ni]));
            atomicMin((int*)&hn[gcol[ni]], __float_as_int(nmc[ni]));
        }
    }
}

// Single block: label histogram in LDS, then validity + mean.
__global__ __launch_bounds__(1024) void k_finalize(const int* __restrict__ labels,
                                                   const float* __restrict__ hp,
                                                   const float* __restrict__ hn,
                                                   float* __restrict__ out) {
    __shared__ int h[NLAB];
    __shared__ float sw[16];
    __shared__ int cw[16];
    const int tid = threadIdx.x;
    if (tid < NLAB) h[tid] = 0;
    __syncthreads();
    for (int i = tid; i < NB; i += 1024) atomicAdd(&h[labels[i]], 1);
    __syncthreads();
    float s = 0.0f;
    int c = 0;
    for (int i = tid; i < NB; i += 1024) {
        const int k = h[labels[i]];
        if (k >= 2 && k < NB) {
            s += fmaxf(hp[i] - hn[i] + 0.5f, 0.0f);
            c += 1;
        }
    }
    #pragma unroll
    for (int m = 1; m < 64; m <<= 1) {
        s += __shfl_xor(s, m);
        c += __shfl_xor(c, m);
    }
    const int wave = tid >> 6, lane = tid & 63;
    if (lane == 0) { sw[wave] = s; cw[wave] = c; }
    __syncthreads();
    if (tid == 0) {
        float S = 0.0f; int C = 0;
        #pragma unroll
        for (int i = 0; i < 16; ++i) { S += sw[i]; C += cw[i]; }
        out[0] = (C > 0) ? (S / (float)C) : 0.0f;
    }
}

extern "C" void kernel_launch(void* const* d_in, const int* in_sizes, int n_in,
                              void* d_out, int out_size, void* d_ws, size_t ws_size,
                              hipStream_t stream) {
    const float* x      = (const float*)d_in[0];
    const int*   labels = (const int*)d_in[1];
    float* ws    = (float*)d_ws;
    float* hp    = ws;
    float* hn    = ws + NB;
    float* norms = ws + 2 * NB;
    ushort* xhi  = (ushort*)(ws + 4 * NB);   // 4 MB bf16 matrix
    float* out   = (float*)d_out;

    k_prep<<<dim3(NB / 4), dim3(256), 0, stream>>>(x, xhi, norms, hp, hn);
    k_dist<<<dim3(528), dim3(256), 0, stream>>>(xhi, labels, norms, hp, hn);
    k_finalize<<<dim3(1), dim3(1024), 0, stream>>>(labels, hp, hn, out);
}

// Round 4
// 102.772 us; speedup vs baseline: 2.7260x; 1.0578x over previous
//
#include <hip/hip_runtime.h>
#include <math.h>

// HardTripletLoss: B=4096, D=512, labels in [0,64), margin 0.5, scalar fp32 out.
// R4: bf16 MFMA Gram, triangular blocks, double-buffered global_load_lds prefetch
// (1 barrier/K-iter, loads drained a full compute-phase later), 512-thread blocks
// (8 waves, 64x32 quadrants) for latency hiding.
//
// ws layout (floats): [0,4096)=hp, [4096,8192)=hn, [8192,12288)=norms,
//                     [12288,16384)=pad, [16384, +2M ushorts)=xhi (4 MB)

#define NB 4096
#define ND 512
#define NLAB 64

typedef __attribute__((ext_vector_type(8))) short short8;
typedef __attribute__((ext_vector_type(4))) float f32x4;

__device__ __forceinline__ ushort bf16rn(float f) {
    unsigned u = __float_as_uint(f);
    u += 0x7FFF + ((u >> 16) & 1);  // round-to-nearest-even
    return (ushort)(u >> 16);
}

__device__ __forceinline__ void gload_lds16(const ushort* g, ushort* l) {
    __builtin_amdgcn_global_load_lds(
        (const __attribute__((address_space(1))) void*)g,
        (__attribute__((address_space(3))) void*)l, 16, 0, 0);
}

// One wave per row: fp32->bf16 convert + exact fp32 norm; init hp/hn.
__global__ __launch_bounds__(256) void k_prep(const float* __restrict__ x,
                                              ushort* __restrict__ xhi,
                                              float* __restrict__ norms,
                                              float* __restrict__ hp,
                                              float* __restrict__ hn) {
    const int wave = threadIdx.x >> 6, lane = threadIdx.x & 63;
    const int row = blockIdx.x * 4 + wave;
    const float* p = x + (size_t)row * ND + lane * 8;
    float4 v0 = *(const float4*)p;
    float4 v1 = *(const float4*)(p + 4);
    ushort h[8];
    h[0] = bf16rn(v0.x); h[1] = bf16rn(v0.y); h[2] = bf16rn(v0.z); h[3] = bf16rn(v0.w);
    h[4] = bf16rn(v1.x); h[5] = bf16rn(v1.y); h[6] = bf16rn(v1.z); h[7] = bf16rn(v1.w);
    *(uint4*)(xhi + (size_t)row * ND + lane * 8) = *(const uint4*)h;
    float s = v0.x*v0.x + v0.y*v0.y + v0.z*v0.z + v0.w*v0.w
            + v1.x*v1.x + v1.y*v1.y + v1.z*v1.z + v1.w*v1.w;
    #pragma unroll
    for (int m = 1; m < 64; m <<= 1) s += __shfl_xor(s, m);
    if (lane == 0) norms[row] = s;
    if (threadIdx.x < 4) {
        hp[blockIdx.x * 4 + threadIdx.x] = 0.0f;
        hn[blockIdx.x * 4 + threadIdx.x] = __int_as_float(0x7F800000);
    }
}

// 128x128 tile, upper-triangle blocks (c>=r), 512 threads = 8 waves, each a
// 64x32 quadrant (4x2 tiles of mfma_f32_16x16x32_bf16). BK=64, double-buffered
// LDS with global_load_lds(16B); XOR chunk swizzle (phys = logical ^ (row&7))
// applied at the SOURCE address, un-applied at fragment reads -> 0 conflicts.
__global__ __launch_bounds__(512, 4) void k_dist(const ushort* __restrict__ xhi,
                                                 const int* __restrict__ labels,
                                                 const float* __restrict__ norms,
                                                 float* __restrict__ hp,
                                                 float* __restrict__ hn) {
    __shared__ ushort As0[128 * 64];  // 16 KB each; distinct arrays so the
    __shared__ ushort As1[128 * 64];  // compiler can disambiguate prefetch
    __shared__ ushort Bs0[128 * 64];  // writes from current-buffer ds_reads
    __shared__ ushort Bs1[128 * 64];

    // Triangular decode, closed form: bid -> (r, c), c >= r, 32x32 grid.
    const int bid = blockIdx.x;
    int r = (int)((65.0f - sqrtf(4225.0f - 8.0f * (float)bid)) * 0.5f);
    int base = r * 32 - (r * (r - 1)) / 2;
    if (bid < base)                { --r; base = r * 32 - (r * (r - 1)) / 2; }
    else if (bid >= base + 32 - r) { ++r; base = r * 32 - (r * (r - 1)) / 2; }
    const int rb = r * 128;
    const int cb = (r + (bid - base)) * 128;

    const int tid = threadIdx.x;
    const int w = tid >> 6, lane = tid & 63;
    const int wr = (w >> 2) * 64;        // 2 row-quadrants
    const int wc = (w & 3) * 32;         // 4 col-quadrants
    const int q = lane >> 4, fr = lane & 15;

    f32x4 acc[4][2];
    #pragma unroll
    for (int mi = 0; mi < 4; ++mi)
        #pragma unroll
        for (int ni = 0; ni < 2; ++ni)
            acc[mi][ni] = (f32x4){0.f, 0.f, 0.f, 0.f};

    // Staging: waves 0-3 -> A tile, waves 4-7 -> B tile; wave covers rows
    // [(w&3)*32, +32) via 4 instrs of 8 rows each. Lane: row += L>>3,
    // phys chunk L&7, source logical chunk (L&7)^(row&7).
    const int srow8 = lane >> 3;
    const int sch = (lane & 7) ^ srow8;
    const int rgrp = (w & 3) * 32;
    const ushort* gbase = xhi + (size_t)(((w >> 2) ? cb : rb) + rgrp + srow8) * ND + sch * 8;
    const bool isB = (w >> 2) != 0;

    #define STAGE(At, Bt, kb)                                                  \
        {                                                                      \
            ushort* sb = (isB ? (Bt) : (At)) + rgrp * 64;                      \
            _Pragma("unroll")                                                  \
            for (int t = 0; t < 4; ++t)                                        \
                gload_lds16(gbase + (size_t)(t * 8) * ND + (kb), sb + t * 8 * 64); \
        }

    #define COMPUTE(At, Bt)                                                    \
        {                                                                      \
            _Pragma("unroll")                                                  \
            for (int kk = 0; kk < 2; ++kk) {                                   \
                short8 a[4], b[2];                                             \
                _Pragma("unroll")                                              \
                for (int mi = 0; mi < 4; ++mi) {                               \
                    const int R = wr + mi * 16 + fr;                           \
                    const int pc = ((kk << 2) | q) ^ (R & 7);                  \
                    a[mi] = *(const short8*)((At) + R * 64 + pc * 8);          \
                }                                                              \
                _Pragma("unroll")                                              \
                for (int ni = 0; ni < 2; ++ni) {                               \
                    const int R = wc + ni * 16 + fr;                           \
                    const int pc = ((kk << 2) | q) ^ (R & 7);                  \
                    b[ni] = *(const short8*)((Bt) + R * 64 + pc * 8);          \
                }                                                              \
                _Pragma("unroll")                                              \
                for (int mi = 0; mi < 4; ++mi)                                 \
                    _Pragma("unroll")                                          \
                    for (int ni = 0; ni < 2; ++ni)                             \
                        acc[mi][ni] = __builtin_amdgcn_mfma_f32_16x16x32_bf16( \
                            a[mi], b[ni], acc[mi][ni], 0, 0, 0);               \
            }                                                                  \
        }

    STAGE(As0, Bs0, 0)
    #pragma unroll
    for (int kb = 0; kb < 8; ++kb) {
        __syncthreads();  // drains this iter's buffer loads (issued 1 phase ago)
        if (kb & 1) {
            if (kb < 7) STAGE(As0, Bs0, (kb + 1) * 64)
            COMPUTE(As1, Bs1)
        } else {
            if (kb < 7) STAGE(As1, Bs1, (kb + 1) * 64)
            COMPUTE(As0, Bs0)
        }
    }

    // Epilogue. C/D layout: col = lane&15, row = (lane>>4)*4 + reg.
    int gcol[2]; float ncol[2]; int lcol[2];
    #pragma unroll
    for (int ni = 0; ni < 2; ++ni) {
        gcol[ni] = cb + wc + ni * 16 + fr;
        ncol[ni] = norms[gcol[ni]];
        lcol[ni] = labels[gcol[ni]];
    }
    float pmc[2], nmc[2];  // column-anchored stats
    #pragma unroll
    for (int ni = 0; ni < 2; ++ni) {
        pmc[ni] = 0.0f;
        nmc[ni] = __int_as_float(0x7F800000);
    }

    #pragma unroll
    for (int mi = 0; mi < 4; ++mi) {
        #pragma unroll
        for (int reg = 0; reg < 4; ++reg) {
            const int grow = rb + wr + mi * 16 + q * 4 + reg;
            const float nr = norms[grow];
            const int lr = labels[grow];
            float pm = 0.0f, nm = __int_as_float(0x7F800000);
            #pragma unroll
            for (int ni = 0; ni < 2; ++ni) {
                float sq = fmaxf(nr + ncol[ni] - 2.0f * acc[mi][ni][reg], 0.0f);
                float dd = sqrtf(sq);
                if (lr == lcol[ni]) {
                    if (grow != gcol[ni]) {
                        pm = fmaxf(pm, dd);
                        pmc[ni] = fmaxf(pmc[ni], dd);
                    }
                } else {
                    nm = fminf(nm, dd);
                    nmc[ni] = fminf(nmc[ni], dd);
                }
            }
            // row stats: reduce over the 16 column-lanes (lane bits 0..3)
            #pragma unroll
            for (int m = 1; m <= 8; m <<= 1) {
                pm = fmaxf(pm, __shfl_xor(pm, m));
                nm = fminf(nm, __shfl_xor(nm, m));
            }
            if (fr == 0) {
                atomicMax((int*)&hp[grow], __float_as_int(pm));
                atomicMin((int*)&hn[grow], __float_as_int(nm));
            }
        }
    }
    // col stats: reduce over the 4 quad-lanes (lane bits 4..5)
    #pragma unroll
    for (int ni = 0; ni < 2; ++ni) {
        #pragma unroll
        for (int m = 16; m <= 32; m <<= 1) {
            pmc[ni] = fmaxf(pmc[ni], __shfl_xor(pmc[ni], m));
            nmc[ni] = fminf(nmc[ni], __shfl_xor(nmc[ni], m));
        }
        if (q == 0) {
            atomicMax((int*)&hp[gcol[ni]], __float_as_int(pmc[ni]));
            atomicMin((int*)&hn[gcol[ni]], __float_as_int(nmc[ni]));
        }
    }
    #undef STAGE
    #undef COMPUTE
}

// Single block: label histogram in LDS, then validity + mean.
__global__ __launch_bounds__(1024) void k_finalize(const int* __restrict__ labels,
                                                   const float* __restrict__ hp,
                                                   const float* __restrict__ hn,
                                                   float* __restrict__ out) {
    __shared__ int h[NLAB];
    __shared__ float sw[16];
    __shared__ int cw[16];
    const int tid = threadIdx.x;
    if (tid < NLAB) h[tid] = 0;
    __syncthreads();
    for (int i = tid; i < NB; i += 1024) atomicAdd(&h[labels[i]], 1);
    __syncthreads();
    float s = 0.0f;
    int c = 0;
    for (int i = tid; i < NB; i += 1024) {
        const int k = h[labels[i]];
        if (k >= 2 && k < NB) {
            s += fmaxf(hp[i] - hn[i] + 0.5f, 0.0f);
            c += 1;
        }
    }
    #pragma unroll
    for (int m = 1; m < 64; m <<= 1) {
        s += __shfl_xor(s, m);
        c += __shfl_xor(c, m);
    }
    const int wave = tid >> 6, lane = tid & 63;
    if (lane == 0) { sw[wave] = s; cw[wave] = c; }
    __syncthreads();
    if (tid == 0) {
        float S = 0.0f; int C = 0;
        #pragma unroll
        for (int i = 0; i < 16; ++i) { S += sw[i]; C += cw[i]; }
        out[0] = (C > 0) ? (S / (float)C) : 0.0f;
    }
}

extern "C" void kernel_launch(void* const* d_in, const int* in_sizes, int n_in,
                              void* d_out, int out_size, void* d_ws, size_t ws_size,
                              hipStream_t stream) {
    const float* x      = (const float*)d_in[0];
    const int*   labels = (const int*)d_in[1];
    float* ws    = (float*)d_ws;
    float* hp    = ws;
    float* hn    = ws + NB;
    float* norms = ws + 2 * NB;
    ushort* xhi  = (ushort*)(ws + 4 * NB);   // 4 MB bf16 matrix
    float* out   = (float*)d_out;

    k_prep<<<dim3(NB / 4), dim3(256), 0, stream>>>(x, xhi, norms, hp, hn);
    k_dist<<<dim3(528), dim3(512), 0, stream>>>(xhi, labels, norms, hp, hn);
    k_finalize<<<dim3(1), dim3(1024), 0, stream>>>(labels, hp, hn, out);
}